// Round 7
// baseline (549.990 us; speedup 1.0000x reference)
//
#include <hip/hip_runtime.h>
#include <cstdint>

typedef unsigned short u16;
typedef __attribute__((ext_vector_type(8))) short bf16x8;
typedef __attribute__((ext_vector_type(4))) float f32x4;

#define DEVI __device__ __forceinline__

// ---- float64 replication of reference ops (np ref computes in f64) ---------
DEVI double pactd(double x, double a) {          // literal op order
    double ax = fabs(x);
    double t  = (ax - fabs(ax - a)) + a;
    double s  = (x > 0.) ? 0.5 : ((x < 0.) ? -0.5 : 0.0);
    return s * t;
}
DEVI double quantd(double x, double r) {         // quant_raw value path, f64
    double xs = x / r;
    xs = fmin(fmax(xs, -0.9921875), 0.9921875);
    double e = rint(xs * 128.0);                 // round half-even
    return (e / 128.0) * r;
}
DEVI double sigd(double x)  { return 1.0 / (1.0 + exp(-x)); }

DEVI u16 bf16bits(float f) {                     // exact for small integers
    return (u16)(__float_as_uint(f) >> 16);
}

// ---- prep: bitsplit activations in FLOAT64 (np-ref precision) --------------
// f64 pact has no [64,128)-binade detritus: pact(x,128)=x exactly -> clean e0.
__global__ void prep_act_d(const float* __restrict__ X, const float* __restrict__ ap,
                           u16* __restrict__ A, int planebase) {
    int idx = blockIdx.x * 256 + threadIdx.x;    // 0 .. 4194303 (= b*1024 + i)
    double a = (double)ap[0];
    double v = (double)X[idx];
    double x = pactd(v, a) / a;
    double xv = x;
    double beta = 1.0;
#pragma unroll
    for (int n = 0; n < 4; n++) {
        double xs = xv / beta;
        xs = fmin(fmax(xs, -0.9921875), 0.9921875);
        double e = rint(xs * 128.0);             // integer in [-127,127]
        A[(size_t)(planebase + n) * 4194304u + idx] = bf16bits((float)e);
        double y = e / 128.0;                    // exact
        xv = xv - y * beta;                      // exact in f64
        beta = beta * 0.5;
    }
}

// ---- prep: quantize + transpose weights -> Wt[proj][n=4096][k=1024] bf16 ---
// Integer result of round(clip(w)*128) is precision-independent: f32 fine.
__global__ void prep_w(const float* __restrict__ W0, const float* __restrict__ W1,
                       u16* __restrict__ Wt) {
    __shared__ float tile[32][33];
    int proj = blockIdx.z;
    const float* W = proj ? W1 : W0;             // [1024][4096] row-major
    int n0 = blockIdx.x * 32, k0 = blockIdx.y * 32;
    int tx = threadIdx.x, ty = threadIdx.y;
#pragma unroll
    for (int i = 0; i < 4; i++)
        tile[ty + i * 8][tx] = W[(size_t)(k0 + ty + i * 8) * 4096 + n0 + tx];
    __syncthreads();
#pragma unroll
    for (int i = 0; i < 4; i++) {
        float w = tile[tx][ty + i * 8];
        float xs = fminf(fmaxf(w, -0.9921875f), 0.9921875f);
        float e = rintf(xs * 128.f);             // Wq*128 integer, exact
        Wt[(size_t)proj * 4194304u + (size_t)(n0 + ty + i * 8) * 1024 + k0 + tx] = bf16bits(e);
    }
}

// ---- prep: bias integers (exact, precision-independent) ---------------------
__global__ void prep_bias(const float* __restrict__ b0, const float* __restrict__ b1,
                          float* __restrict__ Bf) {
    int idx = blockIdx.x * 256 + threadIdx.x;    // 0..8191
    const float* b = (idx < 4096) ? b0 : b1;
    float v = b[idx & 4095];
    float xs = fminf(fmaxf(v, -0.9921875f), 0.9921875f);
    Bf[idx] = rintf(xs * 128.f);
}

// ---- main GEMM: [32768 x 1024] @ Wt^T -> int8 planes E (exact integers) ----
// All values are integers scaled by pow2; fp32 MFMA accumulation is exact
// (|sums| < 2^24). e = rndne(clip(S/128 + Bint, +-127)) — half-even on the
// EXACT value, matching np.round on the f64-exact out_val.
#define GLOAD16(gp, lp) __builtin_amdgcn_global_load_lds( \
    (const __attribute__((address_space(1))) void*)(gp),  \
    (__attribute__((address_space(3))) void*)(lp), 16, 0, 0)

__global__ __launch_bounds__(256) void gemm_planes(
    const u16* __restrict__ A, const u16* __restrict__ Wt,
    const float* __restrict__ Bf, signed char* __restrict__ E) {
    __shared__ __align__(16) u16 lds[8192];      // A tile 8KB | B tile 8KB
    int tid = threadIdx.x;
    int c0 = blockIdx.x * 128;                   // N (gate cols 0..4095)
    int r0 = blockIdx.y * 128;                   // stacked M
    int proj = (r0 >= 16384) ? 1 : 0;

    const u16* gA = A + (size_t)(r0 + (tid >> 2)) * 1024 + (tid & 3) * 8;
    const u16* gB = Wt + (size_t)proj * 4194304u + (size_t)(c0 + (tid >> 2)) * 1024 + (tid & 3) * 8;

    u16* lA0 = lds + tid * 8;
    u16* lA1 = lds + 2048 + tid * 8;
    u16* lB0 = lds + 4096 + tid * 8;
    u16* lB1 = lds + 6144 + tid * 8;

    int w = tid >> 6, l = tid & 63;
    int wm = (w >> 1) * 64, wn = (w & 1) * 64;   // wave quadrant, 64x64
    int quad = l >> 4, lrow = l & 15;

    const u16* fA = lds + (wm + lrow) * 32 + quad * 8;
    const u16* fB = lds + 4096 + (wn + lrow) * 32 + quad * 8;

    f32x4 acc[4][4] = {};

    for (int k0 = 0; k0 < 1024; k0 += 32) {
        GLOAD16(gA, lA0);
        GLOAD16(gA + 64 * 1024, lA1);
        GLOAD16(gB, lB0);
        GLOAD16(gB + 64 * 1024, lB1);
        gA += 32; gB += 32;
        __syncthreads();                         // drains vmcnt -> LDS valid
        bf16x8 af[4], bfr[4];
#pragma unroll
        for (int mt = 0; mt < 4; mt++) af[mt] = *(const bf16x8*)(fA + mt * 512);
#pragma unroll
        for (int nt = 0; nt < 4; nt++) bfr[nt] = *(const bf16x8*)(fB + nt * 512);
#pragma unroll
        for (int mt = 0; mt < 4; mt++)
#pragma unroll
            for (int nt = 0; nt < 4; nt++)
                acc[mt][nt] = __builtin_amdgcn_mfma_f32_16x16x32_bf16(
                    af[mt], bfr[nt], acc[mt][nt], 0, 0, 0);
        __syncthreads();
    }

    // Epilogue: int8 via LDS transpose so stores are h-contiguous coalesced.
    signed char* ctile = (signed char*)lds;      // 128x128 bytes
#pragma unroll
    for (int nt = 0; nt < 4; nt++) {
        int lc = wn + nt * 16 + lrow;            // col = lane&15
        float bb = Bf[proj * 4096 + c0 + lc];
#pragma unroll
        for (int mt = 0; mt < 4; mt++) {
            int lr = wm + mt * 16 + quad * 4;    // row = quad*4+reg
#pragma unroll
            for (int r = 0; r < 4; r++) {
                float t = acc[mt][nt][r] * 0.0078125f + bb;  // exact
                float tc = fminf(fmaxf(t, -127.f), 127.f);
                ctile[(lr + r) * 128 + lc] = (signed char)(int)rintf(tc);
            }
        }
    }
    __syncthreads();
#pragma unroll
    for (int p = 0; p < 4; p++) {
        int lr = (tid >> 3) + p * 32;
        int lc = (tid & 7) * 16;
        *(int4*)(E + (size_t)(r0 + lr) * 4096 + c0 + lc) =
            *(const int4*)(ctile + lr * 128 + lc);
    }
}

// ---- gates: reassemble + elementwise LSTM chain, ALL in FLOAT64 ------------
__global__ void gates_kernel_d(const signed char* __restrict__ E,
                               const float* __restrict__ cx, float* __restrict__ out,
                               const float* __restrict__ a1p, const float* __restrict__ a3p,
                               const float* __restrict__ a4p, const float* __restrict__ a5p,
                               const float* __restrict__ a6p, const float* __restrict__ a7p,
                               const float* __restrict__ a8p, const float* __restrict__ a9p,
                               const float* __restrict__ a10p, const float* __restrict__ a11p) {
    int b = blockIdx.x;
    int h0 = threadIdx.x * 4;                    // 4 h per thread
    double a1 = (double)a1p[0], a3 = (double)a3p[0], a4 = (double)a4p[0];
    double a5 = (double)a5p[0], a6 = (double)a6p[0], a7 = (double)a7p[0];
    double a8 = (double)a8p[0], a9 = (double)a9p[0], a10 = (double)a10p[0];
    double a11 = (double)a11p[0];
    const double betav[4] = {1.0, 0.5, 0.25, 0.125};

    double gate[4][4];                           // [i,j,f,o][h-sub]
#pragma unroll
    for (int g = 0; g < 4; g++) {
        size_t colbase = (size_t)g * 1024 + h0;
        double s1[4] = {0, 0, 0, 0}, s2[4] = {0, 0, 0, 0};
#pragma unroll
        for (int n = 0; n < 4; n++) {
            char4 e1 = *(const char4*)(E + (((size_t)(n * 4096 + b)) << 12) + colbase);
            char4 e2 = *(const char4*)(E + (((size_t)((4 + n) * 4096 + b)) << 12) + colbase);
            double bt = betav[n];
            s1[0] += bt * (double)e1.x; s1[1] += bt * (double)e1.y;
            s1[2] += bt * (double)e1.z; s1[3] += bt * (double)e1.w;
            s2[0] += bt * (double)e2.x; s2[1] += bt * (double)e2.y;
            s2[2] += bt * (double)e2.z; s2[3] += bt * (double)e2.w;
        }
#pragma unroll
        for (int jj = 0; jj < 4; jj++)           // exact: ints scaled by pow2
            gate[g][jj] = (s1[jj] / 128.0) * a1 + (s2[jj] / 128.0) * a11;
    }

    float4 cxv = *(const float4*)(cx + (size_t)b * 1024 + h0);
    double cxa[4] = {(double)cxv.x, (double)cxv.y, (double)cxv.z, (double)cxv.w};
    float nh[4], ncv[4];
#pragma unroll
    for (int jj = 0; jj < 4; jj++) {
        double gi = gate[0][jj], gj = gate[1][jj], gf = gate[2][jj], go = gate[3][jj];
        double fg  = quantd(pactd(sigd(gf), a3), a3);
        double ig  = quantd(pactd(sigd(gi), a4), a4);
        double act = quantd(pactd(tanh(gj), a5), a5);
        double og  = quantd(pactd(sigd(go), a6), a6);
        double gc  = quantd(pactd(cxa[jj] * fg, a7), a7);
        double ai  = quantd(pactd(ig * act, a8), a8);
        double nc  = quantd(pactd(gc + ai, a9), a9);
        double ac  = quantd(pactd(tanh(nc), a10), a10);
        double hh  = quantd(pactd(ac * og, a11), a11);
        nh[jj]  = (float)hh;                     // multiples of 1/32: exact
        ncv[jj] = (float)nc;
    }
    float4 o1 = {nh[0], nh[1], nh[2], nh[3]};
    float4 o2 = {ncv[0], ncv[1], ncv[2], ncv[3]};
    *(float4*)(out + (size_t)b * 1024 + h0) = o1;
    *(float4*)(out + 4194304u + (size_t)b * 1024 + h0) = o2;
}

// ---- launch ----------------------------------------------------------------
extern "C" void kernel_launch(void* const* d_in, const int* in_sizes, int n_in,
                              void* d_out, int out_size, void* d_ws, size_t ws_size,
                              hipStream_t stream) {
    const float* input = (const float*)d_in[0];
    const float* hx    = (const float*)d_in[1];
    const float* cx    = (const float*)d_in[2];
    const float* wih   = (const float*)d_in[3];
    const float* whh   = (const float*)d_in[4];
    const float* bih   = (const float*)d_in[5];
    const float* bhh   = (const float*)d_in[6];
    const float* a1  = (const float*)d_in[7];
    const float* a3  = (const float*)d_in[8];
    const float* a4  = (const float*)d_in[9];
    const float* a5  = (const float*)d_in[10];
    const float* a6  = (const float*)d_in[11];
    const float* a7  = (const float*)d_in[12];
    const float* a8  = (const float*)d_in[13];
    const float* a9  = (const float*)d_in[14];
    const float* a10 = (const float*)d_in[15];
    const float* a11 = (const float*)d_in[16];

    char* ws = (char*)d_ws;
    u16*   A  = (u16*)ws;                                   // 32768*1024*2 = 64 MB
    u16*   Wt = (u16*)(ws + 67108864);                      // 16 MB
    float* Bf = (float*)(ws + 83886080);                    // 32 KB
    signed char* E = (signed char*)(ws + 83918848);         // 128 MB

    prep_act_d<<<16384, 256, 0, stream>>>(input, a1, A, 0);
    prep_act_d<<<16384, 256, 0, stream>>>(hx, a11, A, 4);
    prep_w<<<dim3(128, 32, 2), dim3(32, 8), 0, stream>>>(wih, whh, Wt);
    prep_bias<<<32, 256, 0, stream>>>(bih, bhh, Bf);
    gemm_planes<<<dim3(32, 256), 256, 0, stream>>>(A, Wt, Bf, E);
    gates_kernel_d<<<4096, 256, 0, stream>>>(E, cx, (float*)d_out,
                                             a1, a3, a4, a5, a6, a7, a8, a9, a10, a11);
}

// Round 8
// 427.535 us; speedup vs baseline: 1.2864x; 1.2864x over previous
//
#include <hip/hip_runtime.h>
#include <cstdint>

typedef unsigned short u16;
typedef __attribute__((ext_vector_type(4))) int i32x4;

#define DEVI __device__ __forceinline__

// ---- float64 replication of reference ops (np ref computes in f64) ---------
DEVI double pactd(double x, double a) {          // literal op order
    double ax = fabs(x);
    double t  = (ax - fabs(ax - a)) + a;
    double s  = (x > 0.) ? 0.5 : ((x < 0.) ? -0.5 : 0.0);
    return s * t;
}
DEVI double quantd(double x, double r) {         // quant_raw value path, f64
    double xs = x / r;
    xs = fmin(fmax(xs, -0.9921875), 0.9921875);
    double e = rint(xs * 128.0);                 // round half-even
    return (e / 128.0) * r;
}
DEVI double sigd(double x)  { return 1.0 / (1.0 + exp(-x)); }

// ---- prep: bitsplit activations in FLOAT64 -> int8 planes, char4-packed ----
__global__ void prep_act_d(const float* __restrict__ X, const float* __restrict__ ap,
                           signed char* __restrict__ A, int planebase) {
    int idx4 = (blockIdx.x * 256 + threadIdx.x) * 4;   // 0..4194300 step 4
    double a = (double)ap[0];
    float4 xv4 = *(const float4*)(X + idx4);
    double v[4] = {(double)xv4.x, (double)xv4.y, (double)xv4.z, (double)xv4.w};
    signed char e4[4][4];                        // [n][elem]
#pragma unroll
    for (int el = 0; el < 4; el++) {
        double x = pactd(v[el], a) / a;          // exact pow2 div
        double xv = x;
        double beta = 1.0;
#pragma unroll
        for (int n = 0; n < 4; n++) {
            double xs = xv / beta;               // exact
            xs = fmin(fmax(xs, -0.9921875), 0.9921875);
            double e = rint(xs * 128.0);         // integer in [-127,127]
            e4[n][el] = (signed char)(int)e;
            double y = e / 128.0;                // exact
            xv = xv - y * beta;                  // exact in f64
            beta = beta * 0.5;
        }
    }
#pragma unroll
    for (int n = 0; n < 4; n++)
        *(char4*)(A + (size_t)(planebase + n) * 4194304u + idx4) =
            make_char4(e4[n][0], e4[n][1], e4[n][2], e4[n][3]);
}

// ---- prep: quantize + transpose weights -> Wt[proj][n=4096][k=1024] int8 ---
__global__ void prep_w(const float* __restrict__ W0, const float* __restrict__ W1,
                       signed char* __restrict__ Wt) {
    __shared__ float tile[32][33];
    int proj = blockIdx.z;
    const float* W = proj ? W1 : W0;             // [1024][4096] row-major
    int n0 = blockIdx.x * 32, k0 = blockIdx.y * 32;
    int tx = threadIdx.x, ty = threadIdx.y;
#pragma unroll
    for (int i = 0; i < 4; i++)
        tile[ty + i * 8][tx] = W[(size_t)(k0 + ty + i * 8) * 4096 + n0 + tx];
    __syncthreads();
#pragma unroll
    for (int i = 0; i < 4; i++) {
        float w = tile[tx][ty + i * 8];
        float xs = fminf(fmaxf(w, -0.9921875f), 0.9921875f);
        float e = rintf(xs * 128.f);             // Wq*128 integer, exact
        Wt[(size_t)proj * 4194304u + (size_t)(n0 + ty + i * 8) * 1024 + k0 + tx] =
            (signed char)(int)e;
    }
}

// ---- prep: bias integers (exact) -------------------------------------------
__global__ void prep_bias(const float* __restrict__ b0, const float* __restrict__ b1,
                          float* __restrict__ Bf) {
    int idx = blockIdx.x * 256 + threadIdx.x;    // 0..8191
    const float* b = (idx < 4096) ? b0 : b1;
    float v = b[idx & 4095];
    float xs = fminf(fmaxf(v, -0.9921875f), 0.9921875f);
    Bf[idx] = rintf(xs * 128.f);
}

// ---- main GEMM: int8 MFMA (2x bf16 rate), exact i32 accumulation -----------
// A rows: (proj*4 + n)*4096 + b, K=1024 int8. Wt[proj][n][k] int8.
// e = rndne(clip(S/128 + Bint, +-127)) — exact float path (|t|*128 < 2^24).
#define GLOAD16(gp, lp) __builtin_amdgcn_global_load_lds( \
    (const __attribute__((address_space(1))) void*)(gp),  \
    (__attribute__((address_space(3))) void*)(lp), 16, 0, 0)

__global__ __launch_bounds__(256) void gemm_planes(
    const signed char* __restrict__ A, const signed char* __restrict__ Wt,
    const float* __restrict__ Bf, signed char* __restrict__ E) {
    __shared__ __align__(16) signed char lds[16384]; // A tile 8KB | B tile 8KB
    int tid = threadIdx.x;
    int c0 = blockIdx.x * 128;                   // N (gate cols 0..4095)
    int r0 = blockIdx.y * 128;                   // stacked M
    int proj = (r0 >= 16384) ? 1 : 0;

    // staging: BK=64 -> 64 B/row; 4 lanes x 16 B per row (same geometry as bf16 BK=32)
    const signed char* gA = A + (size_t)(r0 + (tid >> 2)) * 1024 + (tid & 3) * 16;
    const signed char* gB = Wt + (size_t)proj * 4194304u + (size_t)(c0 + (tid >> 2)) * 1024 + (tid & 3) * 16;

    signed char* lA0 = lds + tid * 16;           // A rows 0..63
    signed char* lA1 = lds + 4096 + tid * 16;    // A rows 64..127
    signed char* lB0 = lds + 8192 + tid * 16;
    signed char* lB1 = lds + 12288 + tid * 16;

    int w = tid >> 6, l = tid & 63;
    int wm = (w >> 1) * 64, wn = (w & 1) * 64;   // wave quadrant, 64x64
    int quad = l >> 4, lrow = l & 15;

    // i8 16x16x64 A-frag: 16 consecutive K bytes per lane, k = quad*16 + j
    const signed char* fA = lds + (wm + lrow) * 64 + quad * 16;
    const signed char* fB = lds + 8192 + (wn + lrow) * 64 + quad * 16;

    i32x4 acc[4][4] = {};

    for (int k0 = 0; k0 < 1024; k0 += 64) {      // 16 iterations
        GLOAD16(gA, lA0);
        GLOAD16(gA + 64 * 1024, lA1);
        GLOAD16(gB, lB0);
        GLOAD16(gB + 64 * 1024, lB1);
        gA += 64; gB += 64;
        __syncthreads();                         // drains vmcnt -> LDS valid
        i32x4 af[4], bfr[4];
#pragma unroll
        for (int mt = 0; mt < 4; mt++) af[mt] = *(const i32x4*)(fA + mt * 1024);
#pragma unroll
        for (int nt = 0; nt < 4; nt++) bfr[nt] = *(const i32x4*)(fB + nt * 1024);
#pragma unroll
        for (int mt = 0; mt < 4; mt++)
#pragma unroll
            for (int nt = 0; nt < 4; nt++)
                acc[mt][nt] = __builtin_amdgcn_mfma_i32_16x16x64_i8(
                    af[mt], bfr[nt], acc[mt][nt], 0, 0, 0);
        __syncthreads();
    }

    // Epilogue: int8 via LDS transpose so stores are h-contiguous coalesced.
    signed char* ctile = lds;                    // 128x128 bytes
#pragma unroll
    for (int nt = 0; nt < 4; nt++) {
        int lc = wn + nt * 16 + lrow;            // col = lane&15
        float bb = Bf[proj * 4096 + c0 + lc];
#pragma unroll
        for (int mt = 0; mt < 4; mt++) {
            int lr = wm + mt * 16 + quad * 4;    // row = quad*4+reg
#pragma unroll
            for (int r = 0; r < 4; r++) {
                float t = (float)acc[mt][nt][r] * 0.0078125f + bb;  // exact
                float tc = fminf(fmaxf(t, -127.f), 127.f);
                ctile[(lr + r) * 128 + lc] = (signed char)(int)rintf(tc);
            }
        }
    }
    __syncthreads();
#pragma unroll
    for (int p = 0; p < 4; p++) {
        int lr = (tid >> 3) + p * 32;
        int lc = (tid & 7) * 16;
        *(int4*)(E + (size_t)(r0 + lr) * 4096 + c0 + lc) =
            *(const int4*)(ctile + lr * 128 + lc);
    }
}

// ---- gates: reassemble + elementwise LSTM chain, ALL in FLOAT64 ------------
__global__ void gates_kernel_d(const signed char* __restrict__ E,
                               const float* __restrict__ cx, float* __restrict__ out,
                               const float* __restrict__ a1p, const float* __restrict__ a3p,
                               const float* __restrict__ a4p, const float* __restrict__ a5p,
                               const float* __restrict__ a6p, const float* __restrict__ a7p,
                               const float* __restrict__ a8p, const float* __restrict__ a9p,
                               const float* __restrict__ a10p, const float* __restrict__ a11p) {
    int b = blockIdx.x;
    int h0 = threadIdx.x * 4;                    // 4 h per thread
    double a1 = (double)a1p[0], a3 = (double)a3p[0], a4 = (double)a4p[0];
    double a5 = (double)a5p[0], a6 = (double)a6p[0], a7 = (double)a7p[0];
    double a8 = (double)a8p[0], a9 = (double)a9p[0], a10 = (double)a10p[0];
    double a11 = (double)a11p[0];
    const double betav[4] = {1.0, 0.5, 0.25, 0.125};

    double gate[4][4];                           // [i,j,f,o][h-sub]
#pragma unroll
    for (int g = 0; g < 4; g++) {
        size_t colbase = (size_t)g * 1024 + h0;
        double s1[4] = {0, 0, 0, 0}, s2[4] = {0, 0, 0, 0};
#pragma unroll
        for (int n = 0; n < 4; n++) {
            char4 e1 = *(const char4*)(E + (((size_t)(n * 4096 + b)) << 12) + colbase);
            char4 e2 = *(const char4*)(E + (((size_t)((4 + n) * 4096 + b)) << 12) + colbase);
            double bt = betav[n];
            s1[0] += bt * (double)e1.x; s1[1] += bt * (double)e1.y;
            s1[2] += bt * (double)e1.z; s1[3] += bt * (double)e1.w;
            s2[0] += bt * (double)e2.x; s2[1] += bt * (double)e2.y;
            s2[2] += bt * (double)e2.z; s2[3] += bt * (double)e2.w;
        }
#pragma unroll
        for (int jj = 0; jj < 4; jj++)           // exact: ints scaled by pow2
            gate[g][jj] = (s1[jj] / 128.0) * a1 + (s2[jj] / 128.0) * a11;
    }

    float4 cxv = *(const float4*)(cx + (size_t)b * 1024 + h0);
    double cxa[4] = {(double)cxv.x, (double)cxv.y, (double)cxv.z, (double)cxv.w};
    float nh[4], ncv[4];
#pragma unroll
    for (int jj = 0; jj < 4; jj++) {
        double gi = gate[0][jj], gj = gate[1][jj], gf = gate[2][jj], go = gate[3][jj];
        double fg  = quantd(pactd(sigd(gf), a3), a3);
        double ig  = quantd(pactd(sigd(gi), a4), a4);
        double act = quantd(pactd(tanh(gj), a5), a5);
        double og  = quantd(pactd(sigd(go), a6), a6);
        double gc  = quantd(pactd(cxa[jj] * fg, a7), a7);
        double ai  = quantd(pactd(ig * act, a8), a8);
        double nc  = quantd(pactd(gc + ai, a9), a9);
        double ac  = quantd(pactd(tanh(nc), a10), a10);
        double hh  = quantd(pactd(ac * og, a11), a11);
        nh[jj]  = (float)hh;                     // multiples of 1/32: exact
        ncv[jj] = (float)nc;
    }
    float4 o1 = {nh[0], nh[1], nh[2], nh[3]};
    float4 o2 = {ncv[0], ncv[1], ncv[2], ncv[3]};
    *(float4*)(out + (size_t)b * 1024 + h0) = o1;
    *(float4*)(out + 4194304u + (size_t)b * 1024 + h0) = o2;
}

// ---- launch ----------------------------------------------------------------
extern "C" void kernel_launch(void* const* d_in, const int* in_sizes, int n_in,
                              void* d_out, int out_size, void* d_ws, size_t ws_size,
                              hipStream_t stream) {
    const float* input = (const float*)d_in[0];
    const float* hx    = (const float*)d_in[1];
    const float* cx    = (const float*)d_in[2];
    const float* wih   = (const float*)d_in[3];
    const float* whh   = (const float*)d_in[4];
    const float* bih   = (const float*)d_in[5];
    const float* bhh   = (const float*)d_in[6];
    const float* a1  = (const float*)d_in[7];
    const float* a3  = (const float*)d_in[8];
    const float* a4  = (const float*)d_in[9];
    const float* a5  = (const float*)d_in[10];
    const float* a6  = (const float*)d_in[11];
    const float* a7  = (const float*)d_in[12];
    const float* a8  = (const float*)d_in[13];
    const float* a9  = (const float*)d_in[14];
    const float* a10 = (const float*)d_in[15];
    const float* a11 = (const float*)d_in[16];

    char* ws = (char*)d_ws;
    signed char* A  = (signed char*)ws;                     // 32768*1024 = 32 MB
    signed char* Wt = (signed char*)(ws + 33554432);        // 8 MB
    float*       Bf = (float*)(ws + 41943040);              // 32 KB
    signed char* E  = (signed char*)(ws + 41975808);        // 128 MB

    prep_act_d<<<4096, 256, 0, stream>>>(input, a1, A, 0);
    prep_act_d<<<4096, 256, 0, stream>>>(hx, a11, A, 4);
    prep_w<<<dim3(128, 32, 2), dim3(32, 8), 0, stream>>>(wih, whh, Wt);
    prep_bias<<<32, 256, 0, stream>>>(bih, bhh, Bf);
    gemm_planes<<<dim3(32, 256), 256, 0, stream>>>(A, Wt, Bf, E);
    gates_kernel_d<<<4096, 256, 0, stream>>>(E, cx, (float*)d_out,
                                             a1, a3, a4, a5, a6, a7, a8, a9, a10, a11);
}